// Round 5
// baseline (327.913 us; speedup 1.0000x reference)
//
#include <hip/hip_runtime.h>
#include <math.h>

// ---------------------------------------------------------------------------
// Qwen3.5 TopK Router, MI355X (gfx950).
// R14: convoy decorrelation. R13 showed occupancy 2x (16 waves/CU) with
// MfmaUtil flat at 20% -- both pipes ~50% idle because the 16 waves form
// only TWO barrier-lockstepped convoys. R14 keeps 16 waves/CU but as FOUR
// independent 4-wave blocks (BM 32->16, grid 1024): while one block stages,
// three others can be issuing MFMAs. Also: A-fragments shared across both
// expert strips (5 ds_read/body, was 10), a-index-major mfma order (adjacent
// mfmas hit different accumulators, 1 A-frag live), s_setprio(1) around the
// MFMA cluster (pays only with desynced convoys - T5).
//
// Numerics (unchanged, harness-verified R11/R12/R13):
//   x = sum_i a_i 2^-(4+7i)   (5 int8 slices, |x|<8)
//   w = sum_j c_j 2^-(9+7j)   (5 int8 slices, |w|<0.25)
//   products i+j<=4 -> exact i32 diagonal accumulators, combined in fp64:
//   logit = sum_s acc_s * 2^-(13+7s).  Error ~1e-9.
//
// Fragment layouts (16x16x64 i8, verified by R13 passing):
//   A: lane l -> row l&15,  k = (l>>4)*16 + byte
//   B: lane l -> col l&15,  k = (l>>4)*16 + byte
//   C/D: col = l&15, row = (l>>4)*4 + reg
// ---------------------------------------------------------------------------

constexpr int T = 16384;
constexpr int D = 2048;
constexpr int E = 128;
constexpr int K = 8;

constexpr int BM = 16;        // tokens per block
constexpr int NS = 5;         // int8 slices per fp32
constexpr int NB = D / 64;    // 32 bodies of K=64

typedef int i32x4 __attribute__((ext_vector_type(4)));

#define MFI8(A, B, C) C = __builtin_amdgcn_mfma_i32_16x16x64_i8(A, B, C, 0, 0, 0)

// Exact base-128 digit extraction: x ~= sum_s out[s] / (c * 128^s).
__device__ __forceinline__ void slice5(float x, float c, float ic, int out[NS]) {
    float r = x;
#pragma unroll
    for (int s = 0; s < NS; ++s) {
        float q = rintf(r * c);
        out[s] = (int)q;
        r = fmaf(q, -ic, r);
        c *= 128.f;
        ic *= (1.f / 128.f);
    }
}

// W(E,D) fp32 -> Ws[s][e][k] int8;  w = sum_j Ws[j][e][k] * 2^-(9+7j)
__global__ __launch_bounds__(256)
void w_slice(const float* __restrict__ W, signed char* __restrict__ Ws)
{
    const int e  = blockIdx.x >> 1;
    const int k0 = ((blockIdx.x & 1) << 10) | (threadIdx.x << 2);
    float4 v = *(const float4*)(W + (size_t)e * D + k0);
    int b0[NS], b1[NS], b2[NS], b3[NS];
    slice5(v.x, 512.f, 1.f / 512.f, b0);
    slice5(v.y, 512.f, 1.f / 512.f, b1);
    slice5(v.z, 512.f, 1.f / 512.f, b2);
    slice5(v.w, 512.f, 1.f / 512.f, b3);
#pragma unroll
    for (int s = 0; s < NS; ++s) {
        unsigned lo = __builtin_amdgcn_perm((unsigned)b1[s], (unsigned)b0[s], 0x00000400u);
        unsigned hi = __builtin_amdgcn_perm((unsigned)b3[s], (unsigned)b2[s], 0x00000400u);
        unsigned pk = __builtin_amdgcn_perm(hi, lo, 0x05040100u);
        *(int*)(Ws + (size_t)s * E * D + (size_t)e * D + k0) = (int)pk;
    }
}

// One block = 16 tokens x all 128 experts, full K. 4 waves; wave w owns
// experts [32w, 32w+32) as two 16-expert strips sharing the A fragments.
__global__ __launch_bounds__(256, 4)
void router_fused(const float* __restrict__ X,
                  const signed char* __restrict__ Ws,
                  float* __restrict__ out)
{
    // A staging, double-buffered: [buf][slice][kgroup][token16][16B]
    // Fragment read address = base + lane*16 (contiguous, conflict-free).
    __shared__ __align__(16) signed char As[2][NS][4][16][16];  // 10 KB
    __shared__ double Ld[BM][E];                                // 16 KB

    const int tid = threadIdx.x;
    const long t0 = (long)blockIdx.x * BM;

    // staging roles: thread -> token ar (0..15), k-offset ac (0,4,...,60)
    const int ar = tid >> 4;
    const int ac = (tid & 15) << 2;
    const float* Xp = X + (t0 + ar) * (long)D + ac;

    // mfma roles
    const int l  = tid & 63;
    const int wv = tid >> 6;    // wave 0..3 -> experts [32wv, 32wv+32)
    const int er = l & 15;
    const int kg = l >> 4;

    const signed char* Wp0 = Ws + (size_t)(wv * 32 + er) * D + (size_t)kg * 16;
    const signed char* Wp1 = Wp0 + (size_t)16 * D;

    i32x4 p00 = {}, p01 = {}, p02 = {}, p03 = {}, p04 = {};  // strip 0 diagonals
    i32x4 p10 = {}, p11 = {}, p12 = {}, p13 = {}, p14 = {};  // strip 1 diagonals

    // convert one float4 -> 5 packed slice-dwords into As[buf]
    auto stage = [&](const float4& v, int buf) {
        int q0[NS], q1[NS], q2[NS], q3[NS];
        slice5(v.x, 16.f, 1.f / 16.f, q0);
        slice5(v.y, 16.f, 1.f / 16.f, q1);
        slice5(v.z, 16.f, 1.f / 16.f, q2);
        slice5(v.w, 16.f, 1.f / 16.f, q3);
        int* dst = (int*)&As[buf][0][ac >> 4][ar][ac & 15];
#pragma unroll
        for (int s = 0; s < NS; ++s) {
            unsigned lo = __builtin_amdgcn_perm((unsigned)q1[s], (unsigned)q0[s], 0x00000400u);
            unsigned hi = __builtin_amdgcn_perm((unsigned)q3[s], (unsigned)q2[s], 0x00000400u);
            unsigned pk = __builtin_amdgcn_perm(hi, lo, 0x05040100u);
            dst[s * 256] = (int)pk;   // slice stride = 4*16*16 = 1024 B
        }
    };

    // ---- prologue: stage body 0 into buf 0; prefetch X for body 1 ----
    float4 xv = *(const float4*)(Xp);
    stage(xv, 0);
    xv = *(const float4*)(Xp + 64);
    __syncthreads();

    // ---- main loop: {10 B-loads, stage next, 30 mfma (a-major), barrier} --
    for (int p = 0; p < NB; ++p) {
        const int cur = p & 1;
        const long kb = (long)p * 64;

        // B fragments for both strips (L2-resident 1.3 MB), issued before
        // the VALU conversion phase so their latency hides under it.
        i32x4 b0 = *(const i32x4*)(Wp0 + 0UL * E * D + kb);
        i32x4 b1 = *(const i32x4*)(Wp0 + 1UL * E * D + kb);
        i32x4 b2 = *(const i32x4*)(Wp0 + 2UL * E * D + kb);
        i32x4 b3 = *(const i32x4*)(Wp0 + 3UL * E * D + kb);
        i32x4 b4 = *(const i32x4*)(Wp0 + 4UL * E * D + kb);
        i32x4 c0 = *(const i32x4*)(Wp1 + 0UL * E * D + kb);
        i32x4 c1 = *(const i32x4*)(Wp1 + 1UL * E * D + kb);
        i32x4 c2 = *(const i32x4*)(Wp1 + 2UL * E * D + kb);
        i32x4 c3 = *(const i32x4*)(Wp1 + 3UL * E * D + kb);
        i32x4 c4 = *(const i32x4*)(Wp1 + 4UL * E * D + kb);

        if (p < NB - 1) stage(xv, cur ^ 1);                        // next body
        if (p < NB - 2) xv = *(const float4*)(Xp + (p + 2) * 64);  // body+2

        // a-index-major: one A-fragment live at a time; adjacent mfmas hit
        // different accumulators (no back-to-back same-acc chains).
        const signed char* ap = &As[cur][0][0][0][0] + l * 16;
        __builtin_amdgcn_s_setprio(1);
        i32x4 a;
        a = *(const i32x4*)(ap);            // slice 0
        MFI8(a, b0, p00); MFI8(a, c0, p10);
        MFI8(a, b1, p01); MFI8(a, c1, p11);
        MFI8(a, b2, p02); MFI8(a, c2, p12);
        MFI8(a, b3, p03); MFI8(a, c3, p13);
        MFI8(a, b4, p04); MFI8(a, c4, p14);
        a = *(const i32x4*)(ap + 1024);     // slice 1
        MFI8(a, b0, p01); MFI8(a, c0, p11);
        MFI8(a, b1, p02); MFI8(a, c1, p12);
        MFI8(a, b2, p03); MFI8(a, c2, p13);
        MFI8(a, b3, p04); MFI8(a, c3, p14);
        a = *(const i32x4*)(ap + 2048);     // slice 2
        MFI8(a, b0, p02); MFI8(a, c0, p12);
        MFI8(a, b1, p03); MFI8(a, c1, p13);
        MFI8(a, b2, p04); MFI8(a, c2, p14);
        a = *(const i32x4*)(ap + 3072);     // slice 3
        MFI8(a, b0, p03); MFI8(a, c0, p13);
        MFI8(a, b1, p04); MFI8(a, c1, p14);
        a = *(const i32x4*)(ap + 4096);     // slice 4
        MFI8(a, b0, p04); MFI8(a, c0, p14);
        __builtin_amdgcn_s_setprio(0);

        __syncthreads();
    }

    // combine diagonals in fp64 -> LDS logits.
    // C/D map: col(expert-in-strip) = l&15, row(token) = (l>>4)*4 + reg
#pragma unroll
    for (int r = 0; r < 4; ++r) {
        const int row = kg * 4 + r;
        Ld[row][wv * 32 + er]      = (double)p00[r] * 0x1p-13 + (double)p01[r] * 0x1p-20
                                   + (double)p02[r] * 0x1p-27 + (double)p03[r] * 0x1p-34
                                   + (double)p04[r] * 0x1p-41;
        Ld[row][wv * 32 + 16 + er] = (double)p10[r] * 0x1p-13 + (double)p11[r] * 0x1p-20
                                   + (double)p12[r] * 0x1p-27 + (double)p13[r] * 0x1p-34
                                   + (double)p14[r] * 0x1p-41;
    }
    __syncthreads();

    // ---- epilogue: verified R11/R13 logic; 256 threads = 16 tokens x 16 ----
    float* outL  = out;
    float* outWt = out + (long)T * E;
    float* outId = outWt + (long)T * K;
    const int tx = tid & 15;
    const int tt = tid >> 4;            // token 0..15
    const long t = t0 + tt;

    double acc[8];
#pragma unroll
    for (int j = 0; j < 8; ++j) acc[j] = Ld[tt][(tx << 3) + j];

    double m = acc[0];
#pragma unroll
    for (int j = 1; j < 8; ++j) m = fmax(m, acc[j]);
#pragma unroll
    for (int mask = 1; mask <= 8; mask <<= 1)
        m = fmax(m, __shfl_xor(m, mask, 64));

    float e[8]; float s = 0.f;
#pragma unroll
    for (int j = 0; j < 8; ++j) { e[j] = __expf((float)(acc[j] - m)); s += e[j]; }
#pragma unroll
    for (int mask = 1; mask <= 8; mask <<= 1)
        s += __shfl_xor(s, mask, 64);
    const float inv = 1.f / s;

    float4 st0 = {e[0] * inv, e[1] * inv, e[2] * inv, e[3] * inv};
    float4 st1 = {e[4] * inv, e[5] * inv, e[6] * inv, e[7] * inv};
    *(float4*)&outL[t * E + (tx << 3)]     = st0;
    *(float4*)&outL[t * E + (tx << 3) + 4] = st1;

    // top-8 on fp64 logits (value desc, index asc) == jax.lax.top_k order
    double v[8];
#pragma unroll
    for (int j = 0; j < 8; ++j) v[j] = acc[j];

    float pk[K]; int ik[K]; float tsum = 0.f;
#pragma unroll
    for (int r = 0; r < K; ++r) {
        double bv = -1.0e300; int bi = 0x7fffffff;
#pragma unroll
        for (int j = 0; j < 8; ++j) {
            const int idx = (tx << 3) + j;
            const bool better = (v[j] > bv) || (v[j] == bv && idx < bi);
            bv = better ? v[j] : bv;
            bi = better ? idx : bi;
        }
#pragma unroll
        for (int mask = 1; mask <= 8; mask <<= 1) {
            const double ov = __shfl_xor(bv, mask, 64);
            const int    oi = __shfl_xor(bi, mask, 64);
            const bool better = (ov > bv) || (ov == bv && oi < bi);
            bv = better ? ov : bv;
            bi = better ? oi : bi;
        }
        const float pw = __expf((float)(bv - m)) * inv;
        pk[r] = pw; ik[r] = bi; tsum += pw;
        // static-index knockout (dynamic v[bi&7] would force scratch)
        const bool own  = ((bi >> 3) == tx);
        const int  slot = bi & 7;
#pragma unroll
        for (int j = 0; j < 8; ++j)
            v[j] = (own && j == slot) ? -1.0e300 : v[j];
    }

    if (tx == 0) {
        const float rinv = 1.f / tsum;
#pragma unroll
        for (int r = 0; r < K; ++r) {
            outWt[t * K + r] = pk[r] * rinv;
            outId[t * K + r] = (float)ik[r];
        }
    }
}

extern "C" void kernel_launch(void* const* d_in, const int* in_sizes, int n_in,
                              void* d_out, int out_size, void* d_ws, size_t ws_size,
                              hipStream_t stream)
{
    const float* X = (const float*)d_in[0];
    const float* W = (const float*)d_in[1];
    float* out = (float*)d_out;
    signed char* Ws = (signed char*)d_ws;   // needs NS*E*D = 1.31 MB (<< ws)

    w_slice<<<dim3(E * 2), dim3(256), 0, stream>>>(W, Ws);
    router_fused<<<dim3(T / BM), dim3(256), 0, stream>>>(X, Ws, out);
}

// Round 6
// 252.585 us; speedup vs baseline: 1.2982x; 1.2982x over previous
//
#include <hip/hip_runtime.h>
#include <math.h>

// ---------------------------------------------------------------------------
// Qwen3.5 TopK Router, MI355X (gfx950).
// R15 = R13 skeleton (BM=32, 8 waves, 2 blocks/CU -- best measured: 130us)
// with three targeted fixes, R14's BM=16 experiment reverted:
//  (1) LDS write-slot swizzle: token t, kgroup g stored at slot (t+4g)&15.
//      R13's writes were 4-way bank conflicts (SQ_LDS_BANK_CONFLICT 4.1M);
//      now 2-way (free). Reads stay 2-way.
//  (2) MFMA order a-index-major, interleaved across the two token-tiles:
//      zero same-accumulator back-to-back pairs (R13 had 20/wave/body
//      paying dependent-accumulate latency).
//  (3) K=128 bodies: 10 B-loads at body top (latency hidden under stage
//      VALU), 2 staged chunks, 60 mfma, ONE barrier -> 16 barriers/block
//      (was 32), longer MFMA runs per barrier drain.
//
// Numerics (unchanged, harness-verified R11-R14):
//   x = sum_i a_i 2^-(4+7i)   (5 int8 slices, |x|<8)
//   w = sum_j c_j 2^-(9+7j)   (5 int8 slices, |w|<0.25)
//   products i+j<=4 -> exact i32 diagonal accumulators, combined in fp64:
//   logit = sum_s acc_s * 2^-(13+7s).  Error ~1e-9.
//
// Fragment layouts (16x16x64 i8, verified by R13/R14 passing):
//   A: lane l -> row l&15,  k = (l>>4)*16 + byte
//   B: lane l -> col l&15,  k = (l>>4)*16 + byte
//   C/D: col = l&15, row = (l>>4)*4 + reg
// ---------------------------------------------------------------------------

constexpr int T = 16384;
constexpr int D = 2048;
constexpr int E = 128;
constexpr int K = 8;

constexpr int BM  = 32;        // tokens per block
constexpr int NS  = 5;         // int8 slices per fp32
constexpr int NB2 = D / 128;   // 16 bodies of K=128 (2 chunks of 64)

typedef int i32x4 __attribute__((ext_vector_type(4)));

#define MFI8(A, B, C) C = __builtin_amdgcn_mfma_i32_16x16x64_i8(A, B, C, 0, 0, 0)

// Exact base-128 digit extraction: x ~= sum_s out[s] / (c * 128^s).
__device__ __forceinline__ void slice5(float x, float c, float ic, int out[NS]) {
    float r = x;
#pragma unroll
    for (int s = 0; s < NS; ++s) {
        float q = rintf(r * c);
        out[s] = (int)q;
        r = fmaf(q, -ic, r);
        c *= 128.f;
        ic *= (1.f / 128.f);
    }
}

// W(E,D) fp32 -> Ws[s][e][k] int8;  w = sum_j Ws[j][e][k] * 2^-(9+7j)
__global__ __launch_bounds__(256)
void w_slice(const float* __restrict__ W, signed char* __restrict__ Ws)
{
    const int e  = blockIdx.x >> 1;
    const int k0 = ((blockIdx.x & 1) << 10) | (threadIdx.x << 2);
    float4 v = *(const float4*)(W + (size_t)e * D + k0);
    int b0[NS], b1[NS], b2[NS], b3[NS];
    slice5(v.x, 512.f, 1.f / 512.f, b0);
    slice5(v.y, 512.f, 1.f / 512.f, b1);
    slice5(v.z, 512.f, 1.f / 512.f, b2);
    slice5(v.w, 512.f, 1.f / 512.f, b3);
#pragma unroll
    for (int s = 0; s < NS; ++s) {
        unsigned lo = __builtin_amdgcn_perm((unsigned)b1[s], (unsigned)b0[s], 0x00000400u);
        unsigned hi = __builtin_amdgcn_perm((unsigned)b3[s], (unsigned)b2[s], 0x00000400u);
        unsigned pk = __builtin_amdgcn_perm(hi, lo, 0x05040100u);
        *(int*)(Ws + (size_t)s * E * D + (size_t)e * D + k0) = (int)pk;
    }
}

// One block = 32 tokens x all 128 experts, full K. 8 waves; wave w owns
// experts [16w, 16w+16) as two 16-token tiles sharing B fragments.
__global__ __launch_bounds__(512, 4)
void router_fused(const float* __restrict__ X,
                  const signed char* __restrict__ Ws,
                  float* __restrict__ out)
{
    // A staging, double-buffered, K=128 per buffer:
    // [buf][chunk][slice][tile][kgroup][slot16][16B]   40 KB
    // slot = (token + 4*kgroup) & 15  (write 2-way, read 2-way)
    __shared__ __align__(16) signed char As[2][2][NS][2][4][16][16];
    __shared__ double Ld[BM][E];                                   // 32 KB

    const int tid = threadIdx.x;
    const long t0 = (long)blockIdx.x * BM;

    // staging roles: thread -> token ar (0..31), k-offset ac (0,4,...,60)
    const int ar = tid >> 4;
    const int ac = (tid & 15) << 2;
    const float* Xp = X + (t0 + ar) * (long)D + ac;

    // mfma roles
    const int l  = tid & 63;
    const int wv = tid >> 6;    // wave 0..7 -> experts [16wv, 16wv+16)
    const int er = l & 15;
    const int kg = l >> 4;

    const size_t wbase = (size_t)(wv * 16 + er) * D + (size_t)kg * 16;
    const signed char* Wq0 = Ws + 0UL * E * D + wbase;
    const signed char* Wq1 = Ws + 1UL * E * D + wbase;
    const signed char* Wq2 = Ws + 2UL * E * D + wbase;
    const signed char* Wq3 = Ws + 3UL * E * D + wbase;
    const signed char* Wq4 = Ws + 4UL * E * D + wbase;

    // A-fragment lane offset, including the slot swizzle
    const int loff = kg * 256 + (((er + (kg << 2)) & 15) << 4);

    i32x4 e0 = {}, e1 = {}, e2 = {}, e3 = {}, e4 = {};  // tile 0 diagonals
    i32x4 f0 = {}, f1 = {}, f2 = {}, f3 = {}, f4 = {};  // tile 1 diagonals

    // convert one float4 -> 5 packed slice-dwords into As[buf][chn]
    auto stage = [&](const float4& v, int buf, int chn) {
        int q0[NS], q1[NS], q2[NS], q3[NS];
        slice5(v.x, 16.f, 1.f / 16.f, q0);
        slice5(v.y, 16.f, 1.f / 16.f, q1);
        slice5(v.z, 16.f, 1.f / 16.f, q2);
        slice5(v.w, 16.f, 1.f / 16.f, q3);
        const int slot = ((ar & 15) + ((ac >> 4) << 2)) & 15;
        int* dst = (int*)&As[buf][chn][0][ar >> 4][ac >> 4][slot][ac & 15];
#pragma unroll
        for (int s = 0; s < NS; ++s) {
            unsigned lo = __builtin_amdgcn_perm((unsigned)q1[s], (unsigned)q0[s], 0x00000400u);
            unsigned hi = __builtin_amdgcn_perm((unsigned)q3[s], (unsigned)q2[s], 0x00000400u);
            unsigned pk = __builtin_amdgcn_perm(hi, lo, 0x05040100u);
            dst[s * 512] = (int)pk;   // slice stride = 2048 B
        }
    };

    // 30 mfma for one K=64 chunk: a-index-major, both tiles interleaved.
    // No two consecutive mfmas hit the same accumulator.
    auto chunkMM = [&](const signed char* ap,
                       const i32x4& b0, const i32x4& b1, const i32x4& b2,
                       const i32x4& b3, const i32x4& b4) {
        i32x4 at0, at1;
        at0 = *(const i32x4*)(ap);           at1 = *(const i32x4*)(ap + 1024);
        MFI8(at0, b0, e0); MFI8(at0, b1, e1); MFI8(at0, b2, e2); MFI8(at0, b3, e3); MFI8(at0, b4, e4);
        MFI8(at1, b0, f0); MFI8(at1, b1, f1); MFI8(at1, b2, f2); MFI8(at1, b3, f3); MFI8(at1, b4, f4);
        at0 = *(const i32x4*)(ap + 2048);    at1 = *(const i32x4*)(ap + 3072);
        MFI8(at0, b0, e1); MFI8(at0, b1, e2); MFI8(at0, b2, e3); MFI8(at0, b3, e4);
        MFI8(at1, b0, f1); MFI8(at1, b1, f2); MFI8(at1, b2, f3); MFI8(at1, b3, f4);
        at0 = *(const i32x4*)(ap + 4096);    at1 = *(const i32x4*)(ap + 5120);
        MFI8(at0, b0, e2); MFI8(at0, b1, e3); MFI8(at0, b2, e4);
        MFI8(at1, b0, f2); MFI8(at1, b1, f3); MFI8(at1, b2, f4);
        at0 = *(const i32x4*)(ap + 6144);    at1 = *(const i32x4*)(ap + 7168);
        MFI8(at0, b0, e3); MFI8(at0, b1, e4);
        MFI8(at1, b0, f3); MFI8(at1, b1, f4);
        at0 = *(const i32x4*)(ap + 8192);    at1 = *(const i32x4*)(ap + 9216);
        MFI8(at0, b0, e4);
        MFI8(at1, b0, f4);
    };

    // ---- prologue: stage body 0 (both chunks) into buf 0; prefetch body 1 --
    float4 xv0, xv1;
    {
        float4 x0 = *(const float4*)(Xp);
        float4 x1 = *(const float4*)(Xp + 64);
        stage(x0, 0, 0);
        stage(x1, 0, 1);
        xv0 = *(const float4*)(Xp + 128);
        xv1 = *(const float4*)(Xp + 192);
        __syncthreads();
    }

    // ---- main loop: 16 bodies x {10 B-loads, 2 stages, 60 mfma, 1 barrier}
    for (int p = 0; p < NB2; ++p) {
        const int cur = p & 1;
        const long kb = (long)p * 128;

        // B fragments for both chunks (L2-resident 1.3 MB); their latency
        // hides under the ~700-cycle stage VALU phase below.
        i32x4 b00 = *(const i32x4*)(Wq0 + kb);
        i32x4 b01 = *(const i32x4*)(Wq1 + kb);
        i32x4 b02 = *(const i32x4*)(Wq2 + kb);
        i32x4 b03 = *(const i32x4*)(Wq3 + kb);
        i32x4 b04 = *(const i32x4*)(Wq4 + kb);
        i32x4 b10 = *(const i32x4*)(Wq0 + kb + 64);
        i32x4 b11 = *(const i32x4*)(Wq1 + kb + 64);
        i32x4 b12 = *(const i32x4*)(Wq2 + kb + 64);
        i32x4 b13 = *(const i32x4*)(Wq3 + kb + 64);
        i32x4 b14 = *(const i32x4*)(Wq4 + kb + 64);

        if (p < NB2 - 1) {                    // stage body p+1
            stage(xv0, cur ^ 1, 0);
            stage(xv1, cur ^ 1, 1);
        }
        if (p < NB2 - 2) {                    // prefetch X for body p+2
            xv0 = *(const float4*)(Xp + (p + 2) * 128);
            xv1 = *(const float4*)(Xp + (p + 2) * 128 + 64);
        }

        const signed char* ap =
            (const signed char*)&As[cur][0][0][0][0][0][0] + loff;
        chunkMM(ap,         b00, b01, b02, b03, b04);
        chunkMM(ap + 10240, b10, b11, b12, b13, b14);

        __syncthreads();
    }

    // combine diagonals in fp64 -> LDS logits.
    // C/D map: col(expert) = l&15, row(token-in-tile) = (l>>4)*4 + reg
#pragma unroll
    for (int r = 0; r < 4; ++r) {
        const int row = kg * 4 + r;
        const int col = wv * 16 + er;
        Ld[row][col]      = (double)e0[r] * 0x1p-13 + (double)e1[r] * 0x1p-20
                          + (double)e2[r] * 0x1p-27 + (double)e3[r] * 0x1p-34
                          + (double)e4[r] * 0x1p-41;
        Ld[row + 16][col] = (double)f0[r] * 0x1p-13 + (double)f1[r] * 0x1p-20
                          + (double)f2[r] * 0x1p-27 + (double)f3[r] * 0x1p-34
                          + (double)f4[r] * 0x1p-41;
    }
    __syncthreads();

    // ---- epilogue: verified R11/R13 logic; 512 threads = 32 tokens x 16 ----
    float* outL  = out;
    float* outWt = out + (long)T * E;
    float* outId = outWt + (long)T * K;
    const int tx = tid & 15;
    const int tt = tid >> 4;            // token 0..31
    const long t = t0 + tt;

    double acc[8];
#pragma unroll
    for (int j = 0; j < 8; ++j) acc[j] = Ld[tt][(tx << 3) + j];

    double m = acc[0];
#pragma unroll
    for (int j = 1; j < 8; ++j) m = fmax(m, acc[j]);
#pragma unroll
    for (int mask = 1; mask <= 8; mask <<= 1)
        m = fmax(m, __shfl_xor(m, mask, 64));

    float e[8]; float s = 0.f;
#pragma unroll
    for (int j = 0; j < 8; ++j) { e[j] = __expf((float)(acc[j] - m)); s += e[j]; }
#pragma unroll
    for (int mask = 1; mask <= 8; mask <<= 1)
        s += __shfl_xor(s, mask, 64);
    const float inv = 1.f / s;

    float4 st0 = {e[0] * inv, e[1] * inv, e[2] * inv, e[3] * inv};
    float4 st1 = {e[4] * inv, e[5] * inv, e[6] * inv, e[7] * inv};
    *(float4*)&outL[t * E + (tx << 3)]     = st0;
    *(float4*)&outL[t * E + (tx << 3) + 4] = st1;

    // top-8 on fp64 logits (value desc, index asc) == jax.lax.top_k order
    double v[8];
#pragma unroll
    for (int j = 0; j < 8; ++j) v[j] = acc[j];

    float pk[K]; int ik[K]; float tsum = 0.f;
#pragma unroll
    for (int r = 0; r < K; ++r) {
        double bv = -1.0e300; int bi = 0x7fffffff;
#pragma unroll
        for (int j = 0; j < 8; ++j) {
            const int idx = (tx << 3) + j;
            const bool better = (v[j] > bv) || (v[j] == bv && idx < bi);
            bv = better ? v[j] : bv;
            bi = better ? idx : bi;
        }
#pragma unroll
        for (int mask = 1; mask <= 8; mask <<= 1) {
            const double ov = __shfl_xor(bv, mask, 64);
            const int    oi = __shfl_xor(bi, mask, 64);
            const bool better = (ov > bv) || (ov == bv && oi < bi);
            bv = better ? ov : bv;
            bi = better ? oi : bi;
        }
        const float pw = __expf((float)(bv - m)) * inv;
        pk[r] = pw; ik[r] = bi; tsum += pw;
        // static-index knockout (dynamic v[bi&7] would force scratch)
        const bool own  = ((bi >> 3) == tx);
        const int  slot = bi & 7;
#pragma unroll
        for (int j = 0; j < 8; ++j)
            v[j] = (own && j == slot) ? -1.0e300 : v[j];
    }

    if (tx == 0) {
        const float rinv = 1.f / tsum;
#pragma unroll
        for (int r = 0; r < K; ++r) {
            outWt[t * K + r] = pk[r] * rinv;
            outId[t * K + r] = (float)ik[r];
        }
    }
}

extern "C" void kernel_launch(void* const* d_in, const int* in_sizes, int n_in,
                              void* d_out, int out_size, void* d_ws, size_t ws_size,
                              hipStream_t stream)
{
    const float* X = (const float*)d_in[0];
    const float* W = (const float*)d_in[1];
    float* out = (float*)d_out;
    signed char* Ws = (signed char*)d_ws;   // needs NS*E*D = 1.31 MB (<< ws)

    w_slice<<<dim3(E * 2), dim3(256), 0, stream>>>(W, Ws);
    router_fused<<<dim3(T / BM), dim3(512), 0, stream>>>(X, Ws, out);
}